// Round 9
// baseline (317.224 us; speedup 1.0000x reference)
//
#include <hip/hip_runtime.h>
#include <hip/hip_bf16.h>

// MHA forward. B=4, T=2048, D=1024, H=16, Hd=64. Inputs auto-detected f32/bf16.
// convert x -> fused convert+transpose weights -> QKV GEMM(+bias; Q pre-scaled by
// log2e/8; V written transposed to vT in-epilogue) -> flash attention v9
// (64-key dbuf tiles, 4 blocks/CU, reg-direct PV, MFMA-computed softmax denom)
// -> out GEMM(+bias, dtype-dynamic d_out).
// R4: never cap occupancy via __launch_bounds__ 2nd arg (spill disaster).
// R5: don't interleave P LDS writes into PV chain. R6: keep S live range to one kb.
// R7: single-buffer stalls on per-tile barrier drain.
// R8: 2 waves/SIMD is latency-bound at ~120us regardless of structure; need 4.

typedef __bf16 bf16_t;
typedef __bf16 bf16x8 __attribute__((ext_vector_type(8)));
typedef float f32x4 __attribute__((ext_vector_type(4)));
typedef short short4v __attribute__((ext_vector_type(4)));

#if __has_builtin(__builtin_amdgcn_mfma_f32_16x16x16_bf16)
typedef __bf16 bf16x4 __attribute__((ext_vector_type(4)));
#define MFMA_PV(va, vb, c) __builtin_amdgcn_mfma_f32_16x16x16_bf16( \
    __builtin_bit_cast(bf16x4, (va)), __builtin_bit_cast(bf16x4, (vb)), (c), 0, 0, 0)
#else
#define MFMA_PV(va, vb, c) __builtin_amdgcn_mfma_f32_16x16x16bf16_1k((va), (vb), (c), 0, 0, 0)
#endif

#define DMODEL 1024
#define NH     16
#define HD     64
#define BATCH  4
#define SEQ    2048
#define NTOK   (BATCH * SEQ)      // 8192
#define NOUT   (NTOK * DMODEL)    // 8388608
#define CEXP   0.1803368801111204f   // log2(e)/sqrt(64)

__device__ __forceinline__ void async_ld16(void* lds, const void* g) {
  __builtin_amdgcn_global_load_lds(
      (const __attribute__((address_space(1))) void*)g,
      (__attribute__((address_space(3))) void*)lds, 16, 0, 0);
}

// ------------------------------------------------------------- dtype sniff
__global__ __launch_bounds__(256) void sniff_dtype(
    const uint4* __restrict__ x, int* __restrict__ flag) {
  int t = threadIdx.x;
  int nanish = 0, zc = 0;
  for (int j = 0; j < 4; ++j) {
    uint4 w = x[t + j * 256];
    unsigned u[4] = {w.x, w.y, w.z, w.w};
    for (int k = 0; k < 4; ++k) {
      unsigned lo = u[k] & 0xFFFFu, hi = u[k] >> 16;
      if ((lo & 0x7F80u) == 0x7F80u) nanish++;
      if ((hi & 0x7F80u) == 0x7F80u) nanish++;
      if (lo == 0) zc++;
      if (hi == 0) zc++;
    }
  }
  __shared__ int rn[256], rz[256];
  rn[t] = nanish; rz[t] = zc;
  __syncthreads();
  for (int s = 128; s > 0; s >>= 1) {
    if (t < s) { rn[t] += rn[t + s]; rz[t] += rz[t + s]; }
    __syncthreads();
  }
  if (t == 0) flag[0] = (rn[0] > 4 || rz[0] > 2048) ? 1 : 0;  // 1 = f32 inputs
}

// ------------------------------------------------------------- converters
__global__ __launch_bounds__(256) void conv_to_bf16(
    const void* __restrict__ src, bf16_t* __restrict__ dst, int n,
    const int* __restrict__ flag) {
  int i = (blockIdx.x * 256 + threadIdx.x) * 8;
  if (i >= n) return;
  if (flag[0]) {
    const float4* s = (const float4*)((const float*)src + i);
    float4 a = s[0], b = s[1];
    bf16_t* o = dst + i;
    o[0] = (bf16_t)a.x; o[1] = (bf16_t)a.y; o[2] = (bf16_t)a.z; o[3] = (bf16_t)a.w;
    o[4] = (bf16_t)b.x; o[5] = (bf16_t)b.y; o[6] = (bf16_t)b.z; o[7] = (bf16_t)b.w;
  } else {
    *(uint4*)(dst + i) = *(const uint4*)((const bf16_t*)src + i);
  }
}

__global__ __launch_bounds__(256) void conv_biases(
    const void* __restrict__ sq, const void* __restrict__ so,
    float* __restrict__ dq, float* __restrict__ dofs,
    const int* __restrict__ flag) {
  int i = blockIdx.x * 256 + threadIdx.x;
  if (i < 3072)
    dq[i] = flag[0] ? ((const float*)sq)[i] : (float)((const bf16_t*)sq)[i];
  else {
    int j = i - 3072;
    dofs[j] = flag[0] ? ((const float*)so)[j] : (float)((const bf16_t*)so)[j];
  }
}

// ------------------------------------------------------------- weight transpose
__global__ __launch_bounds__(256) void transpose_w(
    const void* __restrict__ in, bf16_t* __restrict__ out, int R, int C,
    const int* __restrict__ flag) {
  __shared__ bf16_t tile[32][33];
  const int tx = threadIdx.x & 31, ty = threadIdx.x >> 5;
  const int c0 = blockIdx.x * 32, r0 = blockIdx.y * 32;
  if (flag[0]) {
    for (int i = 0; i < 4; ++i) {
      int r = ty + i * 8;
      tile[r][tx] = (bf16_t)((const float*)in)[(size_t)(r0 + r) * C + c0 + tx];
    }
  } else {
    for (int i = 0; i < 4; ++i) {
      int r = ty + i * 8;
      tile[r][tx] = ((const bf16_t*)in)[(size_t)(r0 + r) * C + c0 + tx];
    }
  }
  __syncthreads();
  for (int i = 0; i < 4; ++i) {
    int r = ty + i * 8;
    out[(size_t)(c0 + r) * R + r0 + tx] = tile[tx][r];
  }
}

// ------------------------------------------------------------- GEMM (B^T) + f32 bias
// MODE 1: dyn f32/bf16 per flag. MODE 2: QKV epilogue — Q cols (<1024) scaled by
// CEXP; V cols (>=2048) written transposed into vT[b][h][d][seq]; K cols plain.
template <int MODE>
__global__ __launch_bounds__(256) void gemm_bt_bias(
    const bf16_t* __restrict__ A, const bf16_t* __restrict__ Bt,
    const float* __restrict__ bias, void* __restrict__ Cout,
    int M, int N, int K, const int* __restrict__ flag,
    bf16_t* __restrict__ vT) {
  __shared__ bf16_t sA[128 * 32];
  __shared__ bf16_t sB[128 * 32];
  const int t = threadIdx.x;
  const int wave = t >> 6, lane = t & 63;
  const int quad = lane >> 4, l16 = lane & 15;
  const int bM = blockIdx.y * 128, bN = blockIdx.x * 128;
  const int m0w = (wave >> 1) * 64, n0w = (wave & 1) * 64;
  const int rowS = wave * 16 + (lane >> 2);
  const int kcS = (lane & 3) * 8;

  f32x4 acc[4][4] = {};

  for (int k0 = 0; k0 < K; k0 += 32) {
    for (int r = 0; r < 2; ++r) {
      int row = r * 64 + rowS;
      async_ld16((char*)sA + r * 4096 + wave * 1024,
                 A + (size_t)(bM + row) * K + k0 + kcS);
      async_ld16((char*)sB + r * 4096 + wave * 1024,
                 Bt + (size_t)(bN + row) * K + k0 + kcS);
    }
    __syncthreads();

    bf16x8 af[4], bfr[4];
    for (int i = 0; i < 4; ++i)
      af[i] = *(const bf16x8*)&sA[(m0w + i * 16 + l16) * 32 + quad * 8];
    for (int j = 0; j < 4; ++j)
      bfr[j] = *(const bf16x8*)&sB[(n0w + j * 16 + l16) * 32 + quad * 8];
    for (int i = 0; i < 4; ++i)
      for (int j = 0; j < 4; ++j)
        acc[i][j] = __builtin_amdgcn_mfma_f32_16x16x32_bf16(af[i], bfr[j], acc[i][j], 0, 0, 0);
    __syncthreads();
  }

  const bool f32out = (MODE == 1) && flag[0];
  for (int j = 0; j < 4; ++j) {
    int col = bN + n0w + j * 16 + l16;
    float bv = bias[col];
    for (int i = 0; i < 4; ++i) {
      int row0 = bM + m0w + i * 16 + quad * 4;
      if (MODE == 2 && col >= 2048) {
        // V column -> vT[b][h][d][s], 4 consecutive tokens packed (8B store)
        int hh = (col - 2048) >> 6, dd = (col - 2048) & 63;
        bf16_t o4[4];
        for (int r = 0; r < 4; ++r) o4[r] = (bf16_t)(acc[i][j][r] + bv);
        size_t dst = ((((size_t)(row0 >> 11) * NH + hh) * HD + dd) << 11) | (row0 & 2047);
        *(uint2*)&vT[dst] = *(uint2*)o4;
      } else {
        float scale = (MODE == 2 && col < 1024) ? CEXP : 1.0f;
        for (int r = 0; r < 4; ++r) {
          float v = (acc[i][j][r] + bv) * scale;
          if (f32out) ((float*)Cout)[(size_t)(row0 + r) * N + col] = v;
          else        ((bf16_t*)Cout)[(size_t)(row0 + r) * N + col] = (bf16_t)v;
        }
      }
    }
  }
}

// ------------------------------------------------------------- flash attention v9
// Grid (bh=64, SEQ/128=16) = 1024 blocks = 4 blocks/CU co-resident (LDS 32 KB:
// 64-key K/V tiles, double-buffered) -> 4 waves/SIMD for latency hiding.
// Wave owns 32 q (2 subtiles). kb-outer; S^T via 16x16x32 (Q pre-scaled by CEXP);
// PV via 16x16x16 (B operand == S^T C-layout) straight from exp registers.
// Softmax denom l computed by an extra all-ones-A PV MFMA (accL lanes all hold
// their q's running sum) -> no per-exp VALU adds, no final shuffles.
__global__ __launch_bounds__(256) void attention_v9(
    const bf16_t* __restrict__ qkv, const bf16_t* __restrict__ vT,
    bf16_t* __restrict__ attn) {
  const int t = threadIdx.x;
  const int wave = t >> 6, lane = t & 63;
  const int quad = lane >> 4, l16 = lane & 15;
  const int bh = blockIdx.x, b = bh >> 4, h = bh & 15;
  const int qw = blockIdx.y * 128 + wave * 32;

  __shared__ bf16_t Kt[2][64 * 64];    // [key][d], 16B-chunk XOR swizzle by key&7
  __shared__ bf16_t Vt[2][64 * 64];    // [d][key], 16B-chunk XOR swizzle by d&7

  const bf16_t* qglob = qkv + (size_t)b * SEQ * 3072 + h * 64;
  const bf16_t* kglob = qglob + 1024;
  const bf16_t* vglob = vT + (size_t)bh * HD * SEQ;

  bf16x8 qf[2][2];
  for (int s = 0; s < 2; ++s) {
    const bf16_t* qrow = qglob + (size_t)(qw + s * 16 + l16) * 3072 + quad * 8;
    qf[s][0] = *(const bf16x8*)qrow;
    qf[s][1] = *(const bf16x8*)(qrow + 32);
  }

  f32x4 accO[2][4] = {};
  f32x4 accL[2] = {};
  const short4v ones = {0x3F80, 0x3F80, 0x3F80, 0x3F80};  // bf16 1.0 x4

  // staging: lane -> (row = wave*16 + lane>>3, slot = lane&7); slot holds source
  // chunk slot^(row&7); dest offset = wave*2048 + lane*16 (contiguous per wave)
  const int sRow = lane >> 3, sSlot = lane & 7;

  auto stageKV = [&](int buf, int kt) {
    // K: wave stages keys [wave*16,+16): 2 calls of 8 keys
    for (int j = 0; j < 2; ++j) {
      int keyl = wave * 16 + j * 8 + sRow;
      int gc = sSlot ^ (keyl & 7);
      async_ld16((char*)Kt[buf] + (wave * 16 + j * 8) * 128,
                 kglob + (size_t)(kt + keyl) * 3072 + gc * 8);
    }
    // V: wave stages d [wave*16,+16): 2 calls of 8 d-rows
    for (int j = 0; j < 2; ++j) {
      int d = wave * 16 + j * 8 + sRow;
      int gc = sSlot ^ (d & 7);
      async_ld16((char*)Vt[buf] + (wave * 16 + j * 8) * 128,
                 vglob + (size_t)d * SEQ + kt + gc * 8);
    }
  };

  stageKV(0, 0);

  for (int ti = 0; ti < SEQ / 64; ++ti) {
    const int buf = ti & 1;
    __syncthreads();                       // all DMAs drained + prior reads done
    if (ti + 1 < SEQ / 64) stageKV(buf ^ 1, (ti + 1) * 64);

    const bf16_t* KtB = Kt[buf];
    const bf16_t* VtB = Vt[buf];

    for (int kb = 0; kb < 4; ++kb) {
      const bf16_t* kr = &KtB[(kb * 16 + l16) * 64];
      bf16x8 kf0 = *(const bf16x8*)(kr + ((quad ^ (l16 & 7)) * 8));
      bf16x8 kf1 = *(const bf16x8*)(kr + (((4 + quad) ^ (l16 & 7)) * 8));

      short4v pB[2];
      for (int s = 0; s < 2; ++s) {
        f32x4 z = {0.f, 0.f, 0.f, 0.f};
        f32x4 st = __builtin_amdgcn_mfma_f32_16x16x32_bf16(kf0, qf[s][0], z, 0, 0, 0);
        st = __builtin_amdgcn_mfma_f32_16x16x32_bf16(kf1, qf[s][1], st, 0, 0, 0);
        union { bf16_t hh[4]; short4v s4; } u;
        for (int r = 0; r < 4; ++r)
          u.hh[r] = (bf16_t)__builtin_amdgcn_exp2f(st[r]);   // Q pre-scaled by CEXP
        pB[s] = u.s4;
        accL[s] = MFMA_PV(ones, pB[s], accL[s]);   // denom: row sums of P
      }

      const int chunkbase = kb * 2 + (quad >> 1);
      const int coff = (quad & 1) * 4;
      for (int db = 0; db < 4; ++db) {
        int d = db * 16 + l16;
        short4v vf = *(const short4v*)&VtB[d * 64 + ((chunkbase ^ (d & 7)) * 8) + coff];
        accO[0][db] = MFMA_PV(vf, pB[0], accO[0][db]);
        accO[1][db] = MFMA_PV(vf, pB[1], accO[1][db]);
      }
    }
  }

  for (int s = 0; s < 2; ++s) {
    float inv = 1.f / accL[s][0];          // every lane holds its q's full sum
    size_t tok = (size_t)b * SEQ + qw + s * 16 + l16;
    for (int db = 0; db < 4; ++db) {
      bf16_t o4[4];
      for (int r = 0; r < 4; ++r) o4[r] = (bf16_t)(accO[s][db][r] * inv);
      *(uint2*)&attn[tok * DMODEL + h * HD + db * 16 + quad * 4] = *(uint2*)o4;
    }
  }
}

// ------------------------------------------------------------- launch
extern "C" void kernel_launch(void* const* d_in, const int* in_sizes, int n_in,
                              void* d_out, int out_size, void* d_ws, size_t ws_size,
                              hipStream_t stream) {
  const void* x     = d_in[0];
  const void* w_qkv = d_in[1];
  const void* b_qkv = d_in[2];
  const void* w_out = d_in[3];
  const void* b_out = d_in[4];

  char* ws = (char*)d_ws;
  int*    flag  = (int*)ws;                                    // @0
  bf16_t* wqkvT = (bf16_t*)(ws + 4096);                        // 6.0 MB
  bf16_t* woutT = (bf16_t*)(ws + 6295552);                     // 2.0 MB
  float*  bqkvf = (float*)(ws + 8392704);
  float*  boutf = (float*)(ws + 8404992);
  bf16_t* qkv   = (bf16_t*)(ws + 8409088);                     // 8192x3072 bf16 (50.3 MB)
  bf16_t* xb    = (bf16_t*)(ws + 58740736);                    // 16.8 MB
  bf16_t* attn  = xb;                                          // alias (xb dead after gemm1)
  bf16_t* vTbuf = (bf16_t*)(ws + 75517952);                    // 16.8 MB -> end ~92.3 MB

  sniff_dtype<<<1, 256, 0, stream>>>((const uint4*)x, flag);

  conv_to_bf16<<<NOUT / 2048, 256, 0, stream>>>(x, xb, NOUT, flag);
  conv_biases<<<16, 256, 0, stream>>>(b_qkv, b_out, bqkvf, boutf, flag);

  transpose_w<<<dim3(96, 32), 256, 0, stream>>>(w_qkv, wqkvT, 1024, 3072, flag);
  transpose_w<<<dim3(32, 32), 256, 0, stream>>>(w_out, woutT, 1024, 1024, flag);

  gemm_bt_bias<2><<<dim3(24, 64), 256, 0, stream>>>(
      xb, wqkvT, bqkvf, qkv, NTOK, 3072, 1024, flag, vTbuf);

  attention_v9<<<dim3(BATCH * NH, SEQ / 128), 256, 0, stream>>>(qkv, vTbuf, attn);

  gemm_bt_bias<1><<<dim3(8, 64), 256, 0, stream>>>(
      attn, woutT, boutf, d_out, NTOK, 1024, 1024, flag, nullptr);
}